// Round 1
// baseline (270.346 us; speedup 1.0000x reference)
//
#include <hip/hip_runtime.h>
#include <hip/hip_bf16.h>

#define DEVI __device__ __forceinline__

typedef __attribute__((ext_vector_type(8))) short bf16x8_t;
typedef __attribute__((ext_vector_type(4))) float f32x4_t;
typedef __attribute__((ext_vector_type(4))) short s16x4_t;

// fp32 -> bf16 bits, round-to-nearest-even (matches HW/XLA convert)
static DEVI unsigned short f2b_bits(float f) {
    unsigned int u = __float_as_uint(f);
    unsigned int r = (u + 0x7fffu + ((u >> 16) & 1u)) >> 16;
    return (unsigned short)r;
}

static DEVI void gload16(const short* g, short* l) {
    __builtin_amdgcn_global_load_lds((const __attribute__((address_space(1))) void*)g,
                                     (__attribute__((address_space(3))) void*)l, 16, 0, 0);
}

// ---------------- cast fp32 -> bf16 (elementwise, vectorized) ----------------
__global__ void cast_bf16_k(const float* __restrict__ in, short* __restrict__ out, long n) {
    long i = ((long)blockIdx.x * blockDim.x + threadIdx.x) * 4;
    if (i >= n) return;
    const float4 v = *(const float4*)(in + i);
    s16x4_t o;
    o[0] = (short)f2b_bits(v.x); o[1] = (short)f2b_bits(v.y);
    o[2] = (short)f2b_bits(v.z); o[3] = (short)f2b_bits(v.w);
    *(s16x4_t*)(out + i) = o;
}

// ---------------- transpose + cast: w[K][N] fp32 -> wT[N][K] bf16 ----------------
__global__ void transpose_cast(const float* __restrict__ w, short* __restrict__ wT,
                               int K, int N) {
    __shared__ float tile[32][33];
    const int n0 = blockIdx.x * 32, k0 = blockIdx.y * 32;
    const int tx = threadIdx.x, ty = threadIdx.y;
#pragma unroll
    for (int i = 0; i < 4; ++i)
        tile[ty + 8 * i][tx] = w[(long)(k0 + ty + 8 * i) * N + n0 + tx];
    __syncthreads();
#pragma unroll
    for (int i = 0; i < 4; ++i)
        wT[(long)(n0 + ty + 8 * i) * K + k0 + tx] = (short)f2b_bits(tile[tx][ty + 8 * i]);
}

// ---------------- GEMM: C[M][N] = A[M][K](bf16) @ Bt[N][K](bf16)^T + bias ----------------
// m97 structure: 128x128 tile, BK=32, 4 waves (2x2), 16x16x32 MFMA, global_load_lds w=16
template<int OUT_F32>
__global__ __launch_bounds__(256, 2) void gemm_bt(const short* __restrict__ A,
                                                  const short* __restrict__ Bt,
                                                  const float* __restrict__ bias,
                                                  void* __restrict__ Cv,
                                                  int M, int N, int K) {
    __shared__ __align__(16) short lsA[128 * 32];
    __shared__ __align__(16) short lsB[128 * 32];
    const int tid = threadIdx.x;
    const int lane = tid & 63;
    const int w = tid >> 6;
    const int wr = w >> 1, wc = w & 1;
    const int l15 = lane & 15, lg = lane >> 4;
    const long m0 = (long)blockIdx.y * 128;
    const long n0 = (long)blockIdx.x * 128;

    f32x4_t acc[4][4] = {};

    const int srow = tid >> 2;           // staging row (chunk0), chunk1 = +64
    const int scol = (tid & 3) * 8;      // staging col (elements)
    const short* gA = A + (m0 + srow) * (long)K + scol;
    const short* gB = Bt + (n0 + srow) * (long)K + scol;
    short* lA = lsA + tid * 8;
    short* lB = lsB + tid * 8;

    for (int kt = 0; kt < K; kt += 32) {
        __syncthreads();
        gload16(gA + kt, lA);
        gload16(gA + kt + (long)64 * K, lA + 2048);
        gload16(gB + kt, lB);
        gload16(gB + kt + (long)64 * K, lB + 2048);
        __syncthreads();
        bf16x8_t af[4], bfr[4];
#pragma unroll
        for (int m = 0; m < 4; ++m)
            af[m] = *(const bf16x8_t*)&lsA[(wr * 64 + m * 16 + l15) * 32 + lg * 8];
#pragma unroll
        for (int n = 0; n < 4; ++n)
            bfr[n] = *(const bf16x8_t*)&lsB[(wc * 64 + n * 16 + l15) * 32 + lg * 8];
#pragma unroll
        for (int m = 0; m < 4; ++m)
#pragma unroll
            for (int n = 0; n < 4; ++n)
                acc[m][n] = __builtin_amdgcn_mfma_f32_16x16x32_bf16(af[m], bfr[n], acc[m][n], 0, 0, 0);
    }

#pragma unroll
    for (int n = 0; n < 4; ++n) {
        const long col = n0 + wc * 64 + n * 16 + l15;
        const float bv = bias[col];
#pragma unroll
        for (int m = 0; m < 4; ++m) {
            const long row = m0 + wr * 64 + m * 16 + lg * 4;
#pragma unroll
            for (int j = 0; j < 4; ++j) {
                float v = acc[m][n][j] + bv;
                if (OUT_F32) ((float*)Cv)[(row + j) * N + col] = v;
                else         ((short*)Cv)[(row + j) * N + col] = (short)f2b_bits(v);
            }
        }
    }
}

// ---------------- V transpose: qkv v-part [T][64] -> vt[bh][64][T] ----------------
__global__ __launch_bounds__(256) void vtrans(const short* __restrict__ qkv,
                                              short* __restrict__ vt) {
    __shared__ __align__(16) short tile[64][72];
    const int bh = blockIdx.x >> 5, ti = blockIdx.x & 31;
    const int b = bh >> 4, h = bh & 15;
    const int tid = threadIdx.x;
    const int srow = tid >> 3;          // chunk0 row, chunk1 = +32
    const int scol = (tid & 7) * 8;
#pragma unroll
    for (int p = 0; p < 2; ++p) {
        const int r = srow + 32 * p;
        *(bf16x8_t*)&tile[r][scol] =
            *(const bf16x8_t*)&qkv[((long)b * 2048 + ti * 64 + r) * 3072 + 2048 + h * 64 + scol];
    }
    __syncthreads();
#pragma unroll
    for (int p = 0; p < 2; ++p) {
        const int hd = srow + 32 * p;
        const int tc = scol;
        bf16x8_t v;
#pragma unroll
        for (int i = 0; i < 8; ++i) v[i] = tile[tc + i][hd];
        *(bf16x8_t*)&vt[((long)bh * 64 + hd) * 2048 + ti * 64 + tc] = v;
    }
}

// ---------------- causal flash attention ----------------
// grid: 1024 blocks = (bh:32) x (qtile:32); 4 waves, each owns 16 q-rows
__global__ __launch_bounds__(256, 2) void attn_fwd(const short* __restrict__ qkv,
                                                   const short* __restrict__ vt,
                                                   short* __restrict__ y) {
    __shared__ __align__(16) short lsK[64][72];   // K tile [kv][hd]
    __shared__ __align__(16) short lsV[64][72];   // V^T tile [hd][kv]
    __shared__ __align__(16) short lsP[4][16][72]; // per-wave P [q][kv]
    const int qi = blockIdx.x & 31;
    const int bh = blockIdx.x >> 5;
    const int b = bh >> 4, h = bh & 15;
    const int tid = threadIdx.x, w = tid >> 6, lane = tid & 63;
    const int l15 = lane & 15, lg = lane >> 4;

    // Q fragments (A operand), rows qi*64 + w*16 + l15, k = hd
    const long qrow = (long)qi * 64 + w * 16 + l15;
    bf16x8_t qf[2];
#pragma unroll
    for (int kq = 0; kq < 2; ++kq)
        qf[kq] = *(const bf16x8_t*)&qkv[((long)b * 2048 + qrow) * 3072 + h * 64 + kq * 32 + lg * 8];

    float mrow[4], lrow[4];
    f32x4_t oacc[4] = {};
#pragma unroll
    for (int r = 0; r < 4; ++r) { mrow[r] = -3e38f; lrow[r] = 0.f; }

    const int srow = tid >> 3;
    const int scol = (tid & 7) * 8;

    for (int j = 0; j <= qi; ++j) {
        __syncthreads();
        const long krow = (long)b * 2048 + (long)j * 64;
#pragma unroll
        for (int p = 0; p < 2; ++p) {
            const int r = srow + 32 * p;
            *(bf16x8_t*)&lsK[r][scol] =
                *(const bf16x8_t*)&qkv[(krow + r) * 3072 + 1024 + h * 64 + scol];
            *(bf16x8_t*)&lsV[r][scol] =
                *(const bf16x8_t*)&vt[((long)bh * 64 + r) * 2048 + j * 64 + scol];
        }
        __syncthreads();

        // S = Q K^T
        f32x4_t s[4] = {};
#pragma unroll
        for (int kq = 0; kq < 2; ++kq) {
#pragma unroll
            for (int n = 0; n < 4; ++n) {
                bf16x8_t kf = *(const bf16x8_t*)&lsK[n * 16 + l15][kq * 32 + lg * 8];
                s[n] = __builtin_amdgcn_mfma_f32_16x16x32_bf16(qf[kq], kf, s[n], 0, 0, 0);
            }
        }
        // scale + causal mask
        float sv[4][4];
        const bool diag = (j == qi);
#pragma unroll
        for (int n = 0; n < 4; ++n)
#pragma unroll
            for (int r = 0; r < 4; ++r) {
                float v = s[n][r] * 0.125f;
                if (diag && (n * 16 + l15 > w * 16 + lg * 4 + r)) v = -3e38f;
                sv[n][r] = v;
            }
        // online softmax: row max over 16 lanes (kv%16) x 4 acc tiles
        float pm[4];
#pragma unroll
        for (int r = 0; r < 4; ++r)
            pm[r] = fmaxf(fmaxf(sv[0][r], sv[1][r]), fmaxf(sv[2][r], sv[3][r]));
#pragma unroll
        for (int off = 1; off <= 8; off <<= 1)
#pragma unroll
            for (int r = 0; r < 4; ++r)
                pm[r] = fmaxf(pm[r], __shfl_xor(pm[r], off));
        float mnew[4], alpha[4], ls[4];
#pragma unroll
        for (int r = 0; r < 4; ++r) {
            mnew[r] = fmaxf(mrow[r], pm[r]);
            alpha[r] = __expf(mrow[r] - mnew[r]);
            ls[r] = 0.f;
        }
#pragma unroll
        for (int n = 0; n < 4; ++n)
#pragma unroll
            for (int r = 0; r < 4; ++r) {
                float p = __expf(sv[n][r] - mnew[r]);
                ls[r] += p;
                lsP[w][lg * 4 + r][n * 16 + l15] = (short)f2b_bits(p);
            }
#pragma unroll
        for (int off = 1; off <= 8; off <<= 1)
#pragma unroll
            for (int r = 0; r < 4; ++r)
                ls[r] += __shfl_xor(ls[r], off);
#pragma unroll
        for (int r = 0; r < 4; ++r) {
            lrow[r] = lrow[r] * alpha[r] + ls[r];
            mrow[r] = mnew[r];
        }
#pragma unroll
        for (int n = 0; n < 4; ++n)
#pragma unroll
            for (int r = 0; r < 4; ++r)
                oacc[n][r] *= alpha[r];
        // order wave-private LDS write -> read (cross-lane, no barrier needed)
        asm volatile("s_waitcnt lgkmcnt(0)" ::: "memory");
        // O += P V
#pragma unroll
        for (int kk = 0; kk < 2; ++kk) {
            bf16x8_t pf = *(const bf16x8_t*)&lsP[w][l15][kk * 32 + lg * 8];
#pragma unroll
            for (int n = 0; n < 4; ++n) {
                bf16x8_t vf = *(const bf16x8_t*)&lsV[n * 16 + l15][kk * 32 + lg * 8];
                oacc[n] = __builtin_amdgcn_mfma_f32_16x16x32_bf16(pf, vf, oacc[n], 0, 0, 0);
            }
        }
    }
    // epilogue: y[b, t, h*64+hd] = O / l
#pragma unroll
    for (int n = 0; n < 4; ++n)
#pragma unroll
        for (int r = 0; r < 4; ++r) {
            float ov = oacc[n][r] / lrow[r];
            y[((long)b * 2048 + qi * 64 + w * 16 + lg * 4 + r) * 1024 + h * 64 + n * 16 + l15] =
                (short)f2b_bits(ov);
        }
}

extern "C" void kernel_launch(void* const* d_in, const int* in_sizes, int n_in,
                              void* d_out, int out_size, void* d_ws, size_t ws_size,
                              hipStream_t stream) {
    const float* x     = (const float*)d_in[0];
    const float* w_qkv = (const float*)d_in[1];
    const float* b_qkv = (const float*)d_in[2];
    const float* w_out = (const float*)d_in[3];
    const float* b_out = (const float*)d_in[4];
    float* out = (float*)d_out;

    char* ws = (char*)d_ws;
    size_t off = 0;
    short* xb    = (short*)(ws + off); off += (size_t)4096 * 1024 * 2;   // x bf16
    short* wqkvT = (short*)(ws + off); off += (size_t)3072 * 1024 * 2;   // w_qkv^T bf16
    short* woutT = (short*)(ws + off); off += (size_t)1024 * 1024 * 2;   // w_out^T bf16
    short* qkvb  = (short*)(ws + off); off += (size_t)4096 * 3072 * 2;   // qkv bf16
    short* vt    = (short*)(ws + off); off += (size_t)32 * 64 * 2048 * 2;// V^T per head
    short* yatt  = (short*)(ws + off); off += (size_t)4096 * 1024 * 2;   // attn out bf16

    cast_bf16_k<<<4096, 256, 0, stream>>>(x, xb, 4194304L);
    transpose_cast<<<dim3(96, 32), dim3(32, 8), 0, stream>>>(w_qkv, wqkvT, 1024, 3072);
    transpose_cast<<<dim3(32, 32), dim3(32, 8), 0, stream>>>(w_out, woutT, 1024, 1024);
    gemm_bt<0><<<dim3(24, 32), 256, 0, stream>>>(xb, wqkvT, b_qkv, (void*)qkvb, 4096, 3072, 1024);
    vtrans<<<1024, 256, 0, stream>>>(qkvb, vt);
    attn_fwd<<<1024, 256, 0, stream>>>(qkvb, vt, yatt);
    gemm_bt<1><<<dim3(8, 32), 256, 0, stream>>>(yatt, woutT, b_out, d_out, 4096, 1024, 1024);
}

// Round 2
// 194.914 us; speedup vs baseline: 1.3870x; 1.3870x over previous
//
#include <hip/hip_runtime.h>
#include <hip/hip_bf16.h>

#define DEVI __device__ __forceinline__

typedef __attribute__((ext_vector_type(8))) short bf16x8_t;
typedef __attribute__((ext_vector_type(4))) float f32x4_t;
typedef __attribute__((ext_vector_type(4))) short s16x4_t;
typedef __attribute__((ext_vector_type(2))) unsigned int u32x2_t;

// fp32 -> bf16 bits, round-to-nearest-even
static DEVI unsigned short f2b_bits(float f) {
    unsigned int u = __float_as_uint(f);
    unsigned int r = (u + 0x7fffu + ((u >> 16) & 1u)) >> 16;
    return (unsigned short)r;
}

// packed fp32x2 -> bf16x2 (RNE), lo = s0, hi = s1
static DEVI unsigned int cvtpk_bf16(float lo, float hi) {
    unsigned int r;
    asm("v_cvt_pk_bf16_f32 %0, %1, %2" : "=v"(r) : "v"(lo), "v"(hi));
    return r;
}

static DEVI void gload16(const short* g, short* l) {
    __builtin_amdgcn_global_load_lds((const __attribute__((address_space(1))) void*)g,
                                     (__attribute__((address_space(3))) void*)l, 16, 0, 0);
}

// ---------------- cast fp32 -> bf16 ----------------
__global__ void cast_bf16_k(const float* __restrict__ in, short* __restrict__ out, long n) {
    long i = ((long)blockIdx.x * blockDim.x + threadIdx.x) * 4;
    if (i >= n) return;
    const float4 v = *(const float4*)(in + i);
    s16x4_t o;
    o[0] = (short)f2b_bits(v.x); o[1] = (short)f2b_bits(v.y);
    o[2] = (short)f2b_bits(v.z); o[3] = (short)f2b_bits(v.w);
    *(s16x4_t*)(out + i) = o;
}

// ---------------- transpose + cast: w[K][N] fp32 -> wT[N][K] bf16 ----------------
__global__ void transpose_cast(const float* __restrict__ w, short* __restrict__ wT,
                               int K, int N) {
    __shared__ float tile[32][33];
    const int n0 = blockIdx.x * 32, k0 = blockIdx.y * 32;
    const int tx = threadIdx.x, ty = threadIdx.y;
#pragma unroll
    for (int i = 0; i < 4; ++i)
        tile[ty + 8 * i][tx] = w[(long)(k0 + ty + 8 * i) * N + n0 + tx];
    __syncthreads();
#pragma unroll
    for (int i = 0; i < 4; ++i)
        wT[(long)(n0 + ty + 8 * i) * K + k0 + tx] = (short)f2b_bits(tile[tx][ty + 8 * i]);
}

// ---------------- GEMM: C[M][N] = A @ Bt^T + bias; cols < qcols scaled by qscale ----------------
template<int OUT_F32>
__global__ __launch_bounds__(256, 2) void gemm_bt(const short* __restrict__ A,
                                                  const short* __restrict__ Bt,
                                                  const float* __restrict__ bias,
                                                  void* __restrict__ Cv,
                                                  int M, int N, int K,
                                                  int qcols, float qscale) {
    __shared__ __align__(16) short lsA[128 * 32];
    __shared__ __align__(16) short lsB[128 * 32];
    const int tid = threadIdx.x;
    const int lane = tid & 63;
    const int w = tid >> 6;
    const int wr = w >> 1, wc = w & 1;
    const int l15 = lane & 15, lg = lane >> 4;
    const long m0 = (long)blockIdx.y * 128;
    const long n0 = (long)blockIdx.x * 128;

    f32x4_t acc[4][4] = {};

    const int srow = tid >> 2;
    const int scol = (tid & 3) * 8;
    const short* gA = A + (m0 + srow) * (long)K + scol;
    const short* gB = Bt + (n0 + srow) * (long)K + scol;
    short* lA = lsA + tid * 8;
    short* lB = lsB + tid * 8;

    for (int kt = 0; kt < K; kt += 32) {
        __syncthreads();
        gload16(gA + kt, lA);
        gload16(gA + kt + (long)64 * K, lA + 2048);
        gload16(gB + kt, lB);
        gload16(gB + kt + (long)64 * K, lB + 2048);
        __syncthreads();
        bf16x8_t af[4], bfr[4];
#pragma unroll
        for (int m = 0; m < 4; ++m)
            af[m] = *(const bf16x8_t*)&lsA[(wr * 64 + m * 16 + l15) * 32 + lg * 8];
#pragma unroll
        for (int n = 0; n < 4; ++n)
            bfr[n] = *(const bf16x8_t*)&lsB[(wc * 64 + n * 16 + l15) * 32 + lg * 8];
#pragma unroll
        for (int m = 0; m < 4; ++m)
#pragma unroll
            for (int n = 0; n < 4; ++n)
                acc[m][n] = __builtin_amdgcn_mfma_f32_16x16x32_bf16(af[m], bfr[n], acc[m][n], 0, 0, 0);
    }

#pragma unroll
    for (int n = 0; n < 4; ++n) {
        const long col = n0 + wc * 64 + n * 16 + l15;
        const float bv = bias[col];
        const float sc = (col < qcols) ? qscale : 1.0f;
#pragma unroll
        for (int m = 0; m < 4; ++m) {
            const long row = m0 + wr * 64 + m * 16 + lg * 4;
#pragma unroll
            for (int j = 0; j < 4; ++j) {
                float v = (acc[m][n][j] + bv) * sc;
                if (OUT_F32) ((float*)Cv)[(row + j) * N + col] = v;
                else         ((short*)Cv)[(row + j) * N + col] = (short)f2b_bits(v);
            }
        }
    }
}

// ---------------- V transpose: qkv v-part [T][64] -> vt[bh][64][T] ----------------
__global__ __launch_bounds__(256) void vtrans(const short* __restrict__ qkv,
                                              short* __restrict__ vt) {
    __shared__ __align__(16) short tile[64][72];
    const int bh = blockIdx.x >> 5, ti = blockIdx.x & 31;
    const int b = bh >> 4, h = bh & 15;
    const int tid = threadIdx.x;
    const int srow = tid >> 3;
    const int scol = (tid & 7) * 8;
#pragma unroll
    for (int p = 0; p < 2; ++p) {
        const int r = srow + 32 * p;
        *(bf16x8_t*)&tile[r][scol] =
            *(const bf16x8_t*)&qkv[((long)b * 2048 + ti * 64 + r) * 3072 + 2048 + h * 64 + scol];
    }
    __syncthreads();
#pragma unroll
    for (int p = 0; p < 2; ++p) {
        const int hd = srow + 32 * p;
        const int tc = scol;
        bf16x8_t v;
#pragma unroll
        for (int i = 0; i < 8; ++i) v[i] = tile[tc + i][hd];
        *(bf16x8_t*)&vt[((long)bh * 64 + hd) * 2048 + ti * 64 + tc] = v;
    }
}

// ---------------- causal flash attention (swapped-QK^T, 2-phase pipeline) ----------------
// grid: 1024 blocks; bh = bid&31, t = bid>>5, qi = t<16 ? t : 47-t (per-CU work-sum constant)
// 4 waves x 16 q-rows; KV tile 64; K/V double-buffered LDS, XOR-swizzled (byte ^= (row&7)<<4)
__global__ __launch_bounds__(256, 4) void attn_fwd(const short* __restrict__ qkv,
                                                   const short* __restrict__ vt,
                                                   short* __restrict__ y) {
    __shared__ __align__(16) short lsK[2][64 * 64];
    __shared__ __align__(16) short lsV[2][64 * 64];
    __shared__ __align__(16) short lsP[4 * 16 * 64];
    const int bid = blockIdx.x;
    const int bh = bid & 31;
    const int t = bid >> 5;
    const int qi = (t < 16) ? t : 47 - t;
    const int b = bh >> 4, h = bh & 15;
    const int tid = threadIdx.x, w = tid >> 6, lane = tid & 63;
    const int l15 = lane & 15, lg = lane >> 4;
    const int lg4 = lg * 4;
    const int swz = (l15 & 7) << 4;   // fragment-read XOR (row&7 == l15&7 for all tiles)

    // Q fragments (B operand): Q[q = l15][d] — pre-scaled by 1/8 in GEMM epilogue
    const long qrow = (long)qi * 64 + w * 16 + l15;
    const bf16x8_t qf0 = *(const bf16x8_t*)&qkv[((long)b * 2048 + qrow) * 3072 + h * 64 + lg * 8];
    const bf16x8_t qf1 = *(const bf16x8_t*)&qkv[((long)b * 2048 + qrow) * 3072 + h * 64 + 32 + lg * 8];

    // staging: thread -> LDS linear slot (row=tid>>3, colbytes=(tid&7)*16); source col pre-swizzled
    const int srow = tid >> 3;
    const int scolb = (tid & 7) * 16;
    const int sc = (scolb ^ ((srow & 7) << 4)) >> 1;   // element col, same for row+32
    const short* gK = qkv + ((long)b * 2048 + srow) * 3072 + 1024 + h * 64 + sc;
    const short* gV = vt + ((long)bh * 64 + srow) * 2048 + sc;

    auto STAGE = [&](int jt, int bufi) {
        const short* k0 = gK + (long)jt * 64 * 3072;
        const short* v0 = gV + (long)jt * 64;
        gload16(k0,              &lsK[bufi][tid * 8]);
        gload16(k0 + 32 * 3072,  &lsK[bufi][tid * 8 + 2048]);
        gload16(v0,              &lsV[bufi][tid * 8]);
        gload16(v0 + 32 * 2048,  &lsV[bufi][tid * 8 + 2048]);
    };

    float mrow = -3e38f, lrow = 0.f;
    f32x4_t oacc[4] = {};

    STAGE(0, 0);
    __syncthreads();
    int buf = 0;

    for (int j = 0; j <= qi; ++j) {
        if (j < qi) STAGE(j + 1, buf ^ 1);
        const bool diag = (j == qi);
        const char* Kb = (const char*)lsK[buf];
        const char* Vb = (const char*)lsV[buf];

        // S^T = K * Q^T : s[n] col = q = l15, row = kv = n*16 + lg*4 + r
        f32x4_t s[4] = {};
        const int nlim = diag ? (w + 1) : 4;
#pragma unroll
        for (int kq = 0; kq < 2; ++kq) {
            const bf16x8_t qf = kq ? qf1 : qf0;
#pragma unroll
            for (int n = 0; n < 4; ++n) {
                if (n < nlim) {
                    bf16x8_t kf = *(const bf16x8_t*)(Kb + (n * 16 + l15) * 128 + ((kq * 64 + lg * 16) ^ swz));
                    s[n] = __builtin_amdgcn_mfma_f32_16x16x32_bf16(kf, qf, s[n], 0, 0, 0);
                }
            }
        }

        float p[4][4];
#pragma unroll
        for (int n = 0; n < 4; ++n)
#pragma unroll
            for (int r = 0; r < 4; ++r) p[n][r] = s[n][r];

        if (diag) {
            const int ql = w * 16 + l15 - lg4;   // mask kv_local > q_local
#pragma unroll
            for (int n = 0; n < 4; ++n)
#pragma unroll
                for (int r = 0; r < 4; ++r)
                    if (n * 16 + r > ql) p[n][r] = -3e38f;
        }

        // in-lane max over 16 kv, then combine 4 lane-group replicas
        float pm = -3e38f;
#pragma unroll
        for (int n = 0; n < 4; ++n)
            pm = fmaxf(pm, fmaxf(fmaxf(p[n][0], p[n][1]), fmaxf(p[n][2], p[n][3])));
        pm = fmaxf(pm, __shfl_xor(pm, 16));
        pm = fmaxf(pm, __shfl_xor(pm, 32));

        const float mnew = fmaxf(mrow, pm);
        const float alpha = __expf(mrow - mnew);
        mrow = mnew;

        float lsum = 0.f;
#pragma unroll
        for (int n = 0; n < 4; ++n)
#pragma unroll
            for (int r = 0; r < 4; ++r) {
                p[n][r] = __expf(p[n][r] - mnew);
                lsum += p[n][r];
            }
        lsum += __shfl_xor(lsum, 16);
        lsum += __shfl_xor(lsum, 32);
        lrow = lrow * alpha + lsum;

        // write P[q=l15][kv] (bf16, swizzled): 4 x ds_write_b64
        char* Pb = (char*)lsP + w * 2048 + l15 * 128;
#pragma unroll
        for (int n = 0; n < 4; ++n) {
            u32x2_t dw;
            dw[0] = cvtpk_bf16(p[n][0], p[n][1]);
            dw[1] = cvtpk_bf16(p[n][2], p[n][3]);
            *(u32x2_t*)(Pb + ((n * 32 + lg * 8) ^ swz)) = dw;
        }

        // rescale O (alpha indexed by q = lg*4 + r, fetched from replica lane)
        float ar[4];
#pragma unroll
        for (int r = 0; r < 4; ++r) ar[r] = __shfl(alpha, lg4 + r);
#pragma unroll
        for (int n = 0; n < 4; ++n)
#pragma unroll
            for (int r = 0; r < 4; ++r) oacc[n][r] *= ar[r];

        asm volatile("s_waitcnt lgkmcnt(0)" ::: "memory");   // P writes visible (wave-local)

        // O += P V : A = P[q][kv], B = V^T[d][kv]
#pragma unroll
        for (int kk = 0; kk < 2; ++kk) {
            if (!(diag && kk * 32 > w * 16 + 15)) {
                bf16x8_t pf = *(const bf16x8_t*)(Pb + ((kk * 64 + lg * 16) ^ swz));
#pragma unroll
                for (int n = 0; n < 4; ++n) {
                    bf16x8_t vf = *(const bf16x8_t*)(Vb + (n * 16 + l15) * 128 + ((kk * 64 + lg * 16) ^ swz));
                    oacc[n] = __builtin_amdgcn_mfma_f32_16x16x32_bf16(pf, vf, oacc[n], 0, 0, 0);
                }
            }
        }
        __syncthreads();
        buf ^= 1;
    }

    // epilogue: y[q][d] = O / l
    float lr[4];
#pragma unroll
    for (int r = 0; r < 4; ++r) lr[r] = 1.0f / __shfl(lrow, lg4 + r);
#pragma unroll
    for (int n = 0; n < 4; ++n)
#pragma unroll
        for (int r = 0; r < 4; ++r) {
            const float ov = oacc[n][r] * lr[r];
            y[((long)b * 2048 + qi * 64 + w * 16 + lg4 + r) * 1024 + h * 64 + n * 16 + l15] =
                (short)f2b_bits(ov);
        }
}

extern "C" void kernel_launch(void* const* d_in, const int* in_sizes, int n_in,
                              void* d_out, int out_size, void* d_ws, size_t ws_size,
                              hipStream_t stream) {
    const float* x     = (const float*)d_in[0];
    const float* w_qkv = (const float*)d_in[1];
    const float* b_qkv = (const float*)d_in[2];
    const float* w_out = (const float*)d_in[3];
    const float* b_out = (const float*)d_in[4];

    char* ws = (char*)d_ws;
    size_t off = 0;
    short* xb    = (short*)(ws + off); off += (size_t)4096 * 1024 * 2;
    short* wqkvT = (short*)(ws + off); off += (size_t)3072 * 1024 * 2;
    short* woutT = (short*)(ws + off); off += (size_t)1024 * 1024 * 2;
    short* qkvb  = (short*)(ws + off); off += (size_t)4096 * 3072 * 2;
    short* vt    = (short*)(ws + off); off += (size_t)32 * 64 * 2048 * 2;
    short* yatt  = (short*)(ws + off); off += (size_t)4096 * 1024 * 2;

    cast_bf16_k<<<4096, 256, 0, stream>>>(x, xb, 4194304L);
    transpose_cast<<<dim3(96, 32), dim3(32, 8), 0, stream>>>(w_qkv, wqkvT, 1024, 3072);
    transpose_cast<<<dim3(32, 32), dim3(32, 8), 0, stream>>>(w_out, woutT, 1024, 1024);
    gemm_bt<0><<<dim3(24, 32), 256, 0, stream>>>(xb, wqkvT, b_qkv, (void*)qkvb, 4096, 3072, 1024, 1024, 0.125f);
    vtrans<<<1024, 256, 0, stream>>>(qkvb, vt);
    attn_fwd<<<1024, 256, 0, stream>>>(qkvb, vt, yatt);
    gemm_bt<1><<<dim3(8, 32), 256, 0, stream>>>(yatt, woutT, b_out, d_out, 4096, 1024, 1024, 0, 1.0f);
}